// Round 9
// baseline (209.531 us; speedup 1.0000x reference)
//
#include <hip/hip_runtime.h>

typedef unsigned short u16;
typedef unsigned int u32;
typedef unsigned long long u64;
typedef float v2f __attribute__((ext_vector_type(2)));

#define NBATCH 8
#define NPTS   4096
#define NQTOT  (NBATCH * NPTS)   /* 32768 */
#define KNN    16
#define NBASIS 8
#define OUTM   64
#define NSPLIT 8                 /* windows per block */
#define NHALF  2                 /* blocks (halves) per query group */
#define WIN    (NPTS / (NSPLIT * NHALF))  /* 256 candidates per window */
#define QPB    64
#define TKNN   (QPB * NSPLIT)    /* 512 threads = 8 waves */
#define GRP    8
#define ECAP   64                /* synchronous digest, lambda<=16/phase */
/* per-query LDS row (u64): [0,32) = 2 seed-funnel segs / entry buffer /
 * epilogue scratch; [32,48) = t16 (3rd funnel seg during seed); [48] pad. */
#define ROWSTR 49
#define TOFF   32

// sentinel: d2 = +inf, idx = all-ones (sorts last)
#define SENT 0x7f800000ffffffffull

// Inter-kernel half-result buffer: [NHALF][NQTOT][4] u64 (16 u16 idx/query).
// Static device global (2 MB): allocated at module load -> no hipMalloc, no
// ws_size assumption (R8 grew d_ws use to 2.9 MB, unverified; the container
// failure may have been an OOB ws write — this removes that risk entirely).
__device__ u64 g_part[(size_t)NHALF * NQTOT * 4];

__device__ __forceinline__ void ce(u64& x, u64& y) {
  u64 a = x, b = y;
  bool sw = b < a;
  x = sw ? b : a;
  y = sw ? a : b;
}

// Batcher odd-even mergesort network (fully unrolled).
template <int N>
__device__ __forceinline__ void oems_sort(u64* a) {
#pragma unroll
  for (int p = 1; p < N; p <<= 1) {
#pragma unroll
    for (int k = p; k >= 1; k >>= 1) {
#pragma unroll
      for (int j = k & (p - 1); j + k < N; j += 2 * k) {
#pragma unroll
        for (int i = 0; i < k; ++i) {
          int lo = i + j, hi = i + j + k;
          if (hi < N && (lo / (2 * p)) == (hi / (2 * p)))
            ce(a[lo], a[hi]);
        }
      }
    }
  }
}

// t, a sorted asc -> t = smallest 16 of union, sorted asc.
__device__ __forceinline__ void merge16(u64 t[16], const u64 a[16]) {
  u64 m[16];
#pragma unroll
  for (int i = 0; i < 16; ++i) {
    u64 x = t[i], y = a[15 - i];
    m[i] = (x < y) ? x : y;
  }
#pragma unroll
  for (int k = 8; k >= 1; k >>= 1) {
#pragma unroll
    for (int i = 0; i < 16; ++i) {
      if ((i & k) == 0) ce(m[i], m[i | k]);
    }
  }
#pragma unroll
  for (int i = 0; i < 16; ++i) t[i] = m[i];
}

// Bit-exact d2 pair: ((dx^2+dy^2)+dz^2), no FMA contraction. v_pk ops round
// IEEE-identically to scalar (verified bit-exact vs reference rounds 0-7).
__device__ __forceinline__ v2f d2pair(v2f cx, v2f cy, v2f cz, v2f qx, v2f qy,
                                      v2f qz) {
#pragma clang fp contract(off)
  v2f dx = cx - qx;
  v2f dy = cy - qy;
  v2f dz = cz - qz;
  v2f d2 = (dx * dx + dy * dy) + dz * dz;
  return d2;
}

// Scalar bit-exact d2 (identical rounding to d2pair) — recompute path.
// Proven bit-exact vs reference in rounds 1, 5, 6, 7.
__device__ __forceinline__ float d2s(float cx, float cy, float cz, float qx,
                                     float qy, float qz) {
#pragma clang fp contract(off)
  float dx = cx - qx;
  float dy = cy - qy;
  float dz = cz - qz;
  return (dx * dx + dy * dy) + dz * dz;
}

// publish a sorted 16-list into funnel segment seg of this query's row
__device__ __forceinline__ void pub16(u64* row, int seg, const u64 s[16]) {
#pragma unroll
  for (int e = 0; e < 16; ++e) row[seg * 16 + e] = s[e];
}

// merge funnel segment seg into register list s
__device__ __forceinline__ void mrg16(const u64* row, int seg, u64 s[16]) {
  u64 a[16];
#pragma unroll
  for (int e = 0; e < 16; ++e) a[e] = row[seg * 16 + e];
  merge16(s, a);
}

// Half-kNN kernel: R7's proven structure, but each block covers 8 windows of
// 256 candidates (half of the 16-window split; blockIdx.z = half). Occupancy
// was grid-capped at 512 blocks = 16 waves/CU = 50% ceiling (R7 measured:
// LDS cut 48.6->31.5 KB moved occupancy not at all) -> 1024 blocks gives a
// 32-waves/CU (100%) ceiling with per-thread scan work halved. Output: the
// half's top-16 INDICES (u16) per query; d2 is recomputed bit-exactly in the
// merge kernel. Selection bit-identical (global top-16 = top-16 of union of
// half top-16s; all keys recomputed with identical rounding).
__global__ __launch_bounds__(TKNN) void se3_kernel(
    const float* __restrict__ Xp, const float* __restrict__ Yp,
    const float* __restrict__ Zp, const float4* __restrict__ cpad) {
  __shared__ u64 sBuf[QPB * ROWSTR];  // 25.1 KB
  __shared__ u32 sCnt[QPB];
  __shared__ float sThr[QPB];

  const int b = blockIdx.x;
  const int qg = blockIdx.y;
  const int z = blockIdx.z;  // half id 0/1
  const int tid = threadIdx.x;
  const int ql = tid & 63;
  const int sp = tid >> 6;  // window id within half, wave-uniform
  const int qi = qg * QPB + ql;
  const int base = b * NPTS;

  if (tid < QPB) sCnt[tid] = 0;

  // per-lane query coords (coalesced)
  const float qx = Xp[base + qi];
  const float qy = Yp[base + qi];
  const float qz = Zp[base + qi];
  const v2f qxx = {qx, qx}, qyy = {qy, qy}, qzz = {qz, qz};

  // wave-uniform candidate window -> scalar loads feeding packed math
  const int wbase = __builtin_amdgcn_readfirstlane((z * NSPLIT + sp) * WIN);
  const v2f* xs2 = (const v2f*)(Xp + base + wbase);
  const v2f* ys2 = (const v2f*)(Yp + base + wbase);
  const v2f* zs2 = (const v2f*)(Zp + base + wbase);
  const int sj = qi - wbase;  // self position inside window (may be OOR)

  u64* row = sBuf + (size_t)ql * ROWSTR;

  // ---- Seed: every wave sorts its window's first 16; 3-seg tree merge ----
  {
    u64 s16[16];
    float cd[16];
#pragma unroll
    for (int p = 0; p < 8; ++p) {
      v2f d2 = d2pair(xs2[p], ys2[p], zs2[p], qxx, qyy, qzz);
      cd[2 * p + 0] = d2.x;
      cd[2 * p + 1] = d2.y;
    }
#pragma unroll
    for (int i = 0; i < 16; ++i) {
      u64 v = ((u64)__float_as_uint(cd[i]) << 32) | (u32)(wbase + i);
      s16[i] = (i == sj) ? SENT : v;
    }
    oems_sort<16>(s16);

    // P1: w5,w6,w7 -> segs 0,1,2 (seg2 = t16 region, free during seed)
    if (sp >= 5) pub16(row, sp - 5, s16);
    __syncthreads();
    if (sp >= 1 && sp <= 3) mrg16(row, sp - 1, s16);  // {1,5} {2,6} {3,7}
    __syncthreads();
    // P2: w4 -> seg0, w3 -> seg1
    if (sp == 4) pub16(row, 0, s16);
    if (sp == 3) pub16(row, 1, s16);
    __syncthreads();
    if (sp == 0) mrg16(row, 0, s16);  // {0,4}
    if (sp == 1) mrg16(row, 1, s16);  // {1,5,3,7}
    __syncthreads();
    // P3: w2 -> seg0, w1 -> seg1
    if (sp == 2) pub16(row, 0, s16);
    if (sp == 1) pub16(row, 1, s16);
    __syncthreads();
    if (sp == 0) {
      mrg16(row, 0, s16);  // {0,4,2,6}
      mrg16(row, 1, s16);  // all 8 windows of this half
#pragma unroll
      for (int e = 0; e < 16; ++e) row[TOFF + e] = s16[e];
      sThr[ql] = __uint_as_float((u32)(s16[15] >> 32));
    }
    __syncthreads();
  }
  float thr = sThr[ql];

  // self-exclusion mask precompute (avoids per-candidate j!=qi compare)
  const int selfgrp = (sj >= 0 && sj < WIN) ? (sj >> 3) : -1;
  const u32 selfbit = 1u << (sj & 7);

  // entry buffer: u32 slots [0,64) of the row = u64 slots [0,32)
  u32* ebuf = (u32*)row;

  // ---- Main scan: 4 doubling phases; digest wave rotates (1..4) ----
#pragma unroll
  for (int ph = 0; ph < 4; ++ph) {
    const int cstart = 16 << ph;  // [16,32),[32,64),[64,128),[128,256)
    const int cend = 32 << ph;
#pragma unroll 2
    for (int g = cstart; g < cend; g += GRP) {
      v2f d2p[4];
#pragma unroll
      for (int p = 0; p < 4; ++p)
        d2p[p] = d2pair(xs2[(g >> 1) + p], ys2[(g >> 1) + p],
                        zs2[(g >> 1) + p], qxx, qyy, qzz);
      u32 want = 0;
#pragma unroll
      for (int i = 0; i < GRP; ++i)
        want |= (d2p[i >> 1][i & 1] <= thr) ? (1u << i) : 0u;
      if ((g >> 3) == selfgrp) want &= ~selfbit;
      if (want) {  // ONE u32 entry per group with any hit
        u32 slot = atomicAdd(&sCnt[ql], 1u);
        if (slot < ECAP) ebuf[slot] = (want << 12) | (u32)(wbase + g);
      }
    }
    __syncthreads();
    if (sp == ph + 1) {  // rotating digest wave (1..4), between barriers
      int n = (int)sCnt[ql];
      n = n < ECAP ? n : ECAP;
      if (__any(n > 0)) {
        u64 t16[16];
#pragma unroll
        for (int e = 0; e < 16; ++e) t16[e] = row[TOFF + e];
        int cursor = 0;
        u32 curWant = 0, curBase = 0;
        while (__any(cursor < n || curWant != 0)) {
          // pass 1: decode up to 16 candidate indices (VALU only)
          u32 kidx[16];
          u32 vmask = 0;
#pragma unroll
          for (int e = 0; e < 16; ++e) {
            if (curWant == 0 && cursor < n) {
              u32 ent = ebuf[cursor++];
              curWant = ent >> 12;
              curBase = ent & 0xFFFu;
            }
            if (curWant) {
              int bit = __ffs(curWant) - 1;
              curWant &= curWant - 1;
              kidx[e] = curBase + (u32)bit;
              vmask |= (1u << e);
            } else {
              kidx[e] = 0;
            }
          }
          // pass 2: batched gathers + bit-exact d2 recompute
          u64 a[16];
#pragma unroll
          for (int e = 0; e < 16; ++e) {
            float4 c = cpad[base + (int)kidx[e]];
            float d2 = d2s(c.x, c.y, c.z, qx, qy, qz);
            u64 key = ((u64)__float_as_uint(d2) << 32) | kidx[e];
            a[e] = (vmask & (1u << e)) ? key : SENT;
          }
          oems_sort<16>(a);
          merge16(t16, a);
        }
#pragma unroll
        for (int e = 0; e < 16; ++e) row[TOFF + e] = t16[e];
        sThr[ql] = __uint_as_float((u32)(t16[15] >> 32));
      }
      sCnt[ql] = 0;
    }
    __syncthreads();
    thr = sThr[ql];
  }

  // ---- Write half-result: 16 u16 indices per query, coalesced u64 ----
  if (tid < 256) {
    const int q = tid >> 2;
    const int e0 = (tid & 3) * 4;
    const u64* r = sBuf + (size_t)q * ROWSTR + TOFF;
    u64 pk = 0;
#pragma unroll
    for (int e = 0; e < 4; ++e)
      pk |= (u64)((u32)r[e0 + e] & 0xFFFFu) << (16 * e);
    g_part[((size_t)z * NQTOT + base + qg * QPB + q) * 4 + (tid & 3)] = pk;
  }
}

// Merge the two half top-16s (recomputing d2 bit-exactly from coords) and
// run the R7 epilogue (unchanged). Tiny kernel: ~2.5K VALU ops/query,
// gathers are L2-resident (cpad = 512 KB).
__global__ __launch_bounds__(TKNN) void knn_merge_kernel(
    const float* __restrict__ Xp, const float* __restrict__ Yp,
    const float* __restrict__ Zp, const float4* __restrict__ cpad,
    const float* __restrict__ Wmat, float* __restrict__ out) {
  __shared__ u64 sBuf[QPB * ROWSTR];   // key scratch + t16 + epilogue scratch
  __shared__ u32 sIdx[QPB * 16];       // staged u16 idx (as u32 words)
  __shared__ float sM[QPB * 25];       // reduced M[8][3], stride 25

  const int b = blockIdx.x;
  const int qg = blockIdx.y;
  const int tid = threadIdx.x;
  const int ql = tid & 63;
  const int sp = tid >> 6;
  const int qi = qg * QPB + ql;
  const int base = b * NPTS;

  // ---- Stage both halves' index lists (coalesced u32 loads) ----
  {
    const u32* part32 = (const u32*)g_part;
    const int q = tid >> 3;       // 512 threads / 8 u32 per query-half
    const int s = tid & 7;
#pragma unroll
    for (int h = 0; h < NHALF; ++h) {
      u32 v = part32[((size_t)h * NQTOT + base + qg * QPB + q) * 8 + s];
      sIdx[q * 16 + h * 8 + s] = v;
    }
  }

  // per-lane query coords
  const float qx = Xp[base + qi];
  const float qy = Yp[base + qi];
  const float qz = Zp[base + qi];

  u64* row = sBuf + (size_t)ql * ROWSTR;
  __syncthreads();

  // ---- Recompute keys: thread (ql, sp) -> neighbors sp*4..sp*4+3 ----
  {
    const u16* il = (const u16*)(sIdx + ql * 16);
#pragma unroll
    for (int e = 0; e < 4; ++e) {
      int j = sp * 4 + e;  // [0,16) = half0 sorted, [16,32) = half1 sorted
      u32 idx = il[j];
      float4 c = cpad[base + (int)idx];
      float d2 = d2s(c.x, c.y, c.z, qx, qy, qz);
      row[j] = ((u64)__float_as_uint(d2) << 32) | idx;
    }
  }
  __syncthreads();

  // ---- Merge two sorted 16-lists -> global top-16 ----
  if (sp == 0) {
    u64 t16[16], a[16];
#pragma unroll
    for (int e = 0; e < 16; ++e) t16[e] = row[e];
#pragma unroll
    for (int e = 0; e < 16; ++e) a[e] = row[16 + e];
    merge16(t16, a);
#pragma unroll
    for (int e = 0; e < 16; ++e) row[TOFF + e] = t16[e];
  }
  __syncthreads();

  // ---- Epilogue phase 1 (waves 0-3): partial M over 4 neighbors each ----
  // pv read by all participating threads first; barrier orders reads before
  // scratch writes clobber the t16 region (floats [0,96) incl. [64,96)).
  u64 pv[4];
  if (sp < 4) {
#pragma unroll
    for (int e = 0; e < 4; ++e) pv[e] = row[TOFF + sp * 4 + e];
  }
  __syncthreads();
  if (sp < 4) {
    const int k = sp;
    float4 nc[4];
    float dd[4];
#pragma unroll
    for (int e = 0; e < 4; ++e) {
      nc[e] = cpad[base + (int)(u32)pv[e]];  // independent gathers
      dd[e] = __uint_as_float((u32)(pv[e] >> 32));
    }
    float M[24];
#pragma unroll
    for (int j = 0; j < 24; ++j) M[j] = 0.f;
#pragma unroll
    for (int e = 0; e < 4; ++e) {
      float rx = nc[e].x - qx;  // sender - receiver
      float ry = nc[e].y - qy;
      float rz = nc[e].z - qz;
      float dist = sqrtf(dd[e]);
      float inv = 1.0f / (dist + 1e-8f);
      rx *= inv; ry *= inv; rz *= inv;
      float cut = fminf(dist * 0.1f, 1.0f);
      float g[NBASIS], s = 0.f;
#pragma unroll
      for (int v = 0; v < NBASIS; ++v) {
        float t = cut - (float)v * (1.0f / 7.0f);
        g[v] = __expf(-32.0f * t * t);  // sigma = 1/8 -> 1/(2s^2) = 32
        s += g[v];
      }
      float rs = 1.0f / s;
#pragma unroll
      for (int v = 0; v < NBASIS; ++v) {
        float rb = g[v] * rs;
        M[v * 3 + 0] = fmaf(rb, rx, M[v * 3 + 0]);
        M[v * 3 + 1] = fmaf(rb, ry, M[v * 3 + 1]);
        M[v * 3 + 2] = fmaf(rb, rz, M[v * 3 + 2]);
      }
    }
    float* fp = (float*)row;
#pragma unroll
    for (int c = 0; c < 24; ++c) fp[k * 24 + c] = M[c];  // floats [0,96)
  }
  __syncthreads();

  // ---- Reduce partials: thread (q = ql, comps sp*3..sp*3+2) ----
  {
    const float* fp = (const float*)row;
#pragma unroll
    for (int j0 = 0; j0 < 3; ++j0) {
      int j = sp * 3 + j0;
      float s = fp[0 * 24 + j] + fp[1 * 24 + j] + fp[2 * 24 + j] +
                fp[3 * 24 + j];
      sM[ql * 25 + j] = s;
    }
  }
  __syncthreads();

  // ---- Epilogue phase 2 (all waves): out[q][w*3+m], lane w = ql ----
  float wreg[NBASIS];
#pragma unroll
  for (int v = 0; v < NBASIS; ++v) wreg[v] = Wmat[v * OUTM + ql];
  const float scale = 0.022097086912079608f;  // (1/sqrt(8)) / 16
#pragma unroll
  for (int i = 0; i < 8; ++i) {
    int q = sp * 8 + i;  // wave-uniform -> sM broadcasts
    const float* mq = sM + q * 25;
    float a0 = 0.f, a1 = 0.f, a2 = 0.f;
#pragma unroll
    for (int v = 0; v < NBASIS; ++v) {
      a0 = fmaf(wreg[v], mq[v * 3 + 0], a0);
      a1 = fmaf(wreg[v], mq[v * 3 + 1], a1);
      a2 = fmaf(wreg[v], mq[v * 3 + 2], a2);
    }
    size_t o = (size_t)(base + qg * QPB + q) * (OUTM * 3) + ql * 3;
    out[o + 0] = a0 * scale;
    out[o + 1] = a1 * scale;
    out[o + 2] = a2 * scale;
  }
}

// coords [B*N][3] -> x/y/z planes + float4 array.
__global__ void prep_kernel(const float* __restrict__ coords,
                            float* __restrict__ Xp, float* __restrict__ Yp,
                            float* __restrict__ Zp, float4* __restrict__ cpad) {
  int i = blockIdx.x * 256 + threadIdx.x;
  if (i < NQTOT) {
    float x = coords[3 * i + 0];
    float y = coords[3 * i + 1];
    float z = coords[3 * i + 2];
    Xp[i] = x; Yp[i] = y; Zp[i] = z;
    cpad[i] = make_float4(x, y, z, 0.f);
  }
}

extern "C" void kernel_launch(void* const* d_in, const int* in_sizes, int n_in,
                              void* d_out, int out_size, void* d_ws, size_t ws_size,
                              hipStream_t stream) {
  const float* coords = (const float*)d_in[0];
  const float* Wmat = (const float*)d_in[1];
  float* out = (float*)d_out;

  char* w = (char*)d_ws;
  float* Xp = (float*)(w);               // 128 KB each
  float* Yp = (float*)(w + 131072);
  float* Zp = (float*)(w + 262144);
  float4* cpad = (float4*)(w + 393216);  // 512 KB; ws use ends at 0.92 MB

  prep_kernel<<<dim3((NQTOT + 255) / 256), dim3(256), 0, stream>>>(
      coords, Xp, Yp, Zp, cpad);
  se3_kernel<<<dim3(NBATCH, NPTS / QPB, NHALF), dim3(TKNN), 0, stream>>>(
      Xp, Yp, Zp, cpad);
  knn_merge_kernel<<<dim3(NBATCH, NPTS / QPB), dim3(TKNN), 0, stream>>>(
      Xp, Yp, Zp, cpad, Wmat, out);
}

// Round 10
// 164.822 us; speedup vs baseline: 1.2713x; 1.2713x over previous
//
#include <hip/hip_runtime.h>

typedef unsigned int u32;
typedef unsigned long long u64;
typedef float v2f __attribute__((ext_vector_type(2)));

#define NBATCH 8
#define NPTS   4096
#define NQTOT  (NBATCH * NPTS)   /* 32768 */
#define KNN    16
#define NBASIS 8
#define OUTM   64
#define NSPLIT 8
#define WIN    (NPTS / NSPLIT)   /* 512 candidates per window */
#define QPB    64
#define TKNN   (QPB * NSPLIT)    /* 512 threads = 8 waves */
#define GRP    8
#define ECAP   64                /* synchronous digest: thr never stale ->
                                  * lambda ~16/phase, cap 64 proven (R3/R5/R7) */
/* Admission margin for the contracted-FMA scan d2: |fma_d2 - exact_d2| <=
 * ~2ulp of ~40 ~= 1e-5; eps = 2e-4 gives 20x headroom. Admission becomes a
 * SUPERSET of the exact test; the digest recomputes exact d2 and discards
 * extras -> selection stays bit-identical. */
#define THR_EPS 2e-4f
/* per-query LDS row (u64): [0,32) = 2 seed-funnel segments / 64-u32 entry
 * buffer / epilogue scratch; [32,48) = t16 (also 3rd funnel seg during seed);
 * [48] pad. 32 KB/block; R7 measured: LDS is NOT the occupancy limiter. */
#define ROWSTR 49
#define TOFF   32

// sentinel: d2 = +inf, idx = all-ones (sorts last)
#define SENT 0x7f800000ffffffffull

__device__ __forceinline__ void ce(u64& x, u64& y) {
  u64 a = x, b = y;
  bool sw = b < a;
  x = sw ? b : a;
  y = sw ? a : b;
}

// Batcher odd-even mergesort network (fully unrolled).
template <int N>
__device__ __forceinline__ void oems_sort(u64* a) {
#pragma unroll
  for (int p = 1; p < N; p <<= 1) {
#pragma unroll
    for (int k = p; k >= 1; k >>= 1) {
#pragma unroll
      for (int j = k & (p - 1); j + k < N; j += 2 * k) {
#pragma unroll
        for (int i = 0; i < k; ++i) {
          int lo = i + j, hi = i + j + k;
          if (hi < N && (lo / (2 * p)) == (hi / (2 * p)))
            ce(a[lo], a[hi]);
        }
      }
    }
  }
}

// t, a sorted asc -> t = smallest 16 of union, sorted asc.
__device__ __forceinline__ void merge16(u64 t[16], const u64 a[16]) {
  u64 m[16];
#pragma unroll
  for (int i = 0; i < 16; ++i) {
    u64 x = t[i], y = a[15 - i];
    m[i] = (x < y) ? x : y;
  }
#pragma unroll
  for (int k = 8; k >= 1; k >>= 1) {
#pragma unroll
    for (int i = 0; i < 16; ++i) {
      if ((i & k) == 0) ce(m[i], m[i | k]);
    }
  }
#pragma unroll
  for (int i = 0; i < 16; ++i) t[i] = m[i];
}

// Bit-exact d2 pair: ((dx^2+dy^2)+dz^2), no FMA contraction. v_pk ops round
// IEEE-identically to scalar (verified bit-exact vs reference rounds 0-7).
// Used where d2 becomes a SORT KEY (seed).
__device__ __forceinline__ v2f d2pair(v2f cx, v2f cy, v2f cz, v2f qx, v2f qy,
                                      v2f qz) {
#pragma clang fp contract(off)
  v2f dx = cx - qx;
  v2f dy = cy - qy;
  v2f dz = cz - qz;
  v2f d2 = (dx * dx + dy * dy) + dz * dz;
  return d2;
}

// Contracted d2 pair for the scan ADMISSION TEST only (never a sort key):
// 3 sub + 1 mul + 2 fma packed ops vs 5 mul/add in the exact form. Compared
// against thr+THR_EPS -> admission superset; digest re-derives exact keys.
__device__ __forceinline__ v2f d2fast(v2f cx, v2f cy, v2f cz, v2f qx, v2f qy,
                                      v2f qz) {
  v2f dx = cx - qx;
  v2f dy = cy - qy;
  v2f dz = cz - qz;
  return __builtin_elementwise_fma(
      dz, dz, __builtin_elementwise_fma(dy, dy, dx * dx));
}

// Scalar bit-exact d2 (identical rounding to d2pair) — digest recompute.
// Proven bit-exact vs reference in rounds 1, 5, 6, 7.
__device__ __forceinline__ float d2s(float cx, float cy, float cz, float qx,
                                     float qy, float qz) {
#pragma clang fp contract(off)
  float dx = cx - qx;
  float dy = cy - qy;
  float dz = cz - qz;
  return (dx * dx + dy * dy) + dz * dz;
}

// publish a sorted 16-list into funnel segment seg of this query's row
__device__ __forceinline__ void pub16(u64* row, int seg, const u64 s[16]) {
#pragma unroll
  for (int e = 0; e < 16; ++e) row[seg * 16 + e] = s[e];
}

// merge funnel segment seg into register list s
__device__ __forceinline__ void mrg16(const u64* row, int seg, u64 s[16]) {
  u64 a[16];
#pragma unroll
  for (int e = 0; e < 16; ++e) a[e] = row[seg * 16 + e];
  merge16(s, a);
}

// Fused kNN + tensor-product features — R7 structure (proven best, 114.6us):
// 512-thread blocks, 8 windows, synchronous rotating digest, group-encoded
// entries, 32KB LDS. R10 edit: scan admission uses contracted-FMA d2 with a
// +2e-4 margin (superset; digest discards extras via exact keys). All three
// parallelism-structure changes (R2 wider block, R6 9-wave concurrent, R9
// split grid) REGRESSED — concurrency does not convert to throughput here;
// only scan-issue reductions have ever moved the needle. NO __launch_bounds__
// min-waves (forced VGPR -> scratch spills, measured).
__global__ __launch_bounds__(TKNN) void se3_kernel(
    const float* __restrict__ Xp, const float* __restrict__ Yp,
    const float* __restrict__ Zp, const float4* __restrict__ cpad,
    const float* __restrict__ Wmat, float* __restrict__ out) {
  __shared__ u64 sBuf[QPB * ROWSTR];  // 25.1 KB
  __shared__ u32 sCnt[QPB];
  __shared__ float sThr[QPB];
  __shared__ float sM[QPB * 25];      // reduced M[8][3], stride 25

  const int b = blockIdx.x;
  const int qg = blockIdx.y;
  const int tid = threadIdx.x;
  const int ql = tid & 63;
  const int sp = tid >> 6;  // window id, wave-uniform
  const int qi = qg * QPB + ql;
  const int base = b * NPTS;

  if (tid < QPB) sCnt[tid] = 0;

  // per-lane query coords (coalesced)
  const float qx = Xp[base + qi];
  const float qy = Yp[base + qi];
  const float qz = Zp[base + qi];
  const v2f qxx = {qx, qx}, qyy = {qy, qy}, qzz = {qz, qz};

  // wave-uniform candidate window -> scalar loads feeding packed math
  const int wbase = __builtin_amdgcn_readfirstlane(sp * WIN);
  const v2f* xs2 = (const v2f*)(Xp + base + wbase);
  const v2f* ys2 = (const v2f*)(Yp + base + wbase);
  const v2f* zs2 = (const v2f*)(Zp + base + wbase);
  const int sj = qi - wbase;  // self position inside window (may be OOR)

  u64* row = sBuf + (size_t)ql * ROWSTR;

  // ---- Seed: every wave sorts its window's first 16; 3-seg tree merge ----
  // (exact d2 — these values become sort keys directly)
  {
    u64 s16[16];
    float cd[16];
#pragma unroll
    for (int p = 0; p < 8; ++p) {
      v2f d2 = d2pair(xs2[p], ys2[p], zs2[p], qxx, qyy, qzz);
      cd[2 * p + 0] = d2.x;
      cd[2 * p + 1] = d2.y;
    }
#pragma unroll
    for (int i = 0; i < 16; ++i) {
      u64 v = ((u64)__float_as_uint(cd[i]) << 32) | (u32)(wbase + i);
      s16[i] = (i == sj) ? SENT : v;
    }
    oems_sort<16>(s16);

    // P1: w5,w6,w7 -> segs 0,1,2 (seg2 = t16 region, free during seed)
    if (sp >= 5) pub16(row, sp - 5, s16);
    __syncthreads();
    if (sp >= 1 && sp <= 3) mrg16(row, sp - 1, s16);  // {1,5} {2,6} {3,7}
    __syncthreads();
    // P2: w4 -> seg0, w3 -> seg1
    if (sp == 4) pub16(row, 0, s16);
    if (sp == 3) pub16(row, 1, s16);
    __syncthreads();
    if (sp == 0) mrg16(row, 0, s16);  // {0,4}
    if (sp == 1) mrg16(row, 1, s16);  // {1,5,3,7}
    __syncthreads();
    // P3: w2 -> seg0, w1 -> seg1
    if (sp == 2) pub16(row, 0, s16);
    if (sp == 1) pub16(row, 1, s16);
    __syncthreads();
    if (sp == 0) {
      mrg16(row, 0, s16);  // {0,4,2,6}
      mrg16(row, 1, s16);  // all 8 windows
#pragma unroll
      for (int e = 0; e < 16; ++e) row[TOFF + e] = s16[e];
      sThr[ql] = __uint_as_float((u32)(s16[15] >> 32));
    }
    __syncthreads();
  }
  float thr = sThr[ql];
  float thrm = thr + THR_EPS;  // margin for contracted admission test

  // self-exclusion mask precompute (avoids per-candidate j!=qi compare)
  const int selfgrp = (sj >= 0 && sj < WIN) ? (sj >> 3) : -1;
  const u32 selfbit = 1u << (sj & 7);

  // entry buffer: u32 slots [0,64) of the row = u64 slots [0,32)
  u32* ebuf = (u32*)row;

  // ---- Main scan: doubling phases; digest wave rotates (1..5) ----
#pragma unroll
  for (int ph = 0; ph < 5; ++ph) {
    const int cstart = 16 << ph;  // [16,32),[32,64),...,[256,512)
    const int cend = 32 << ph;
#pragma unroll 2
    for (int g = cstart; g < cend; g += GRP) {
      v2f d2p[4];
#pragma unroll
      for (int p = 0; p < 4; ++p)
        d2p[p] = d2fast(xs2[(g >> 1) + p], ys2[(g >> 1) + p],
                        zs2[(g >> 1) + p], qxx, qyy, qzz);
      u32 want = 0;
#pragma unroll
      for (int i = 0; i < GRP; ++i)
        want |= (d2p[i >> 1][i & 1] <= thrm) ? (1u << i) : 0u;
      if ((g >> 3) == selfgrp) want &= ~selfbit;
      if (want) {  // ONE u32 entry per group with any hit
        u32 slot = atomicAdd(&sCnt[ql], 1u);
        if (slot < ECAP) ebuf[slot] = (want << 12) | (u32)(wbase + g);
      }
    }
    __syncthreads();
    if (sp == ph + 1) {  // rotating digest wave (1..5), between barriers
      int n = (int)sCnt[ql];
      n = n < ECAP ? n : ECAP;
      if (__any(n > 0)) {
        u64 t16[16];
#pragma unroll
        for (int e = 0; e < 16; ++e) t16[e] = row[TOFF + e];
        int cursor = 0;
        u32 curWant = 0, curBase = 0;
        while (__any(cursor < n || curWant != 0)) {
          // pass 1: decode up to 16 candidate indices (VALU only)
          u32 kidx[16];
          u32 vmask = 0;
#pragma unroll
          for (int e = 0; e < 16; ++e) {
            if (curWant == 0 && cursor < n) {
              u32 ent = ebuf[cursor++];
              curWant = ent >> 12;
              curBase = ent & 0xFFFu;
            }
            if (curWant) {
              int bit = __ffs(curWant) - 1;
              curWant &= curWant - 1;
              kidx[e] = curBase + (u32)bit;
              vmask |= (1u << e);
            } else {
              kidx[e] = 0;
            }
          }
          // pass 2: batched gathers + bit-exact d2 recompute
          u64 a[16];
#pragma unroll
          for (int e = 0; e < 16; ++e) {
            float4 c = cpad[base + (int)kidx[e]];
            float d2 = d2s(c.x, c.y, c.z, qx, qy, qz);
            u64 key = ((u64)__float_as_uint(d2) << 32) | kidx[e];
            a[e] = (vmask & (1u << e)) ? key : SENT;
          }
          oems_sort<16>(a);
          merge16(t16, a);
        }
#pragma unroll
        for (int e = 0; e < 16; ++e) row[TOFF + e] = t16[e];
        sThr[ql] = __uint_as_float((u32)(t16[15] >> 32));
      }
      sCnt[ql] = 0;
    }
    __syncthreads();
    thr = sThr[ql];
    thrm = thr + THR_EPS;
  }

  // ---- Epilogue phase 1 (waves 0-3): partial M over 4 neighbors each ----
  // pv is read by ALL participating threads first; the barrier then orders
  // those reads before scratch writes clobber the t16 region (row floats
  // [0,96) = the whole row incl. t16 floats [64,96), all dead afterward).
  u64 pv[4];
  if (sp < 4) {
#pragma unroll
    for (int e = 0; e < 4; ++e) pv[e] = row[TOFF + sp * 4 + e];
  }
  __syncthreads();
  if (sp < 4) {
    const int k = sp;
    float4 nc[4];
    float dd[4];
#pragma unroll
    for (int e = 0; e < 4; ++e) {
      nc[e] = cpad[base + (int)(u32)pv[e]];  // independent gathers
      dd[e] = __uint_as_float((u32)(pv[e] >> 32));
    }
    float M[24];
#pragma unroll
    for (int j = 0; j < 24; ++j) M[j] = 0.f;
#pragma unroll
    for (int e = 0; e < 4; ++e) {
      float rx = nc[e].x - qx;  // sender - receiver
      float ry = nc[e].y - qy;
      float rz = nc[e].z - qz;
      float dist = sqrtf(dd[e]);
      float inv = 1.0f / (dist + 1e-8f);
      rx *= inv; ry *= inv; rz *= inv;
      float cut = fminf(dist * 0.1f, 1.0f);
      float g[NBASIS], s = 0.f;
#pragma unroll
      for (int v = 0; v < NBASIS; ++v) {
        float t = cut - (float)v * (1.0f / 7.0f);
        g[v] = __expf(-32.0f * t * t);  // sigma = 1/8 -> 1/(2s^2) = 32
        s += g[v];
      }
      float rs = 1.0f / s;
#pragma unroll
      for (int v = 0; v < NBASIS; ++v) {
        float rb = g[v] * rs;
        M[v * 3 + 0] = fmaf(rb, rx, M[v * 3 + 0]);
        M[v * 3 + 1] = fmaf(rb, ry, M[v * 3 + 1]);
        M[v * 3 + 2] = fmaf(rb, rz, M[v * 3 + 2]);
      }
    }
    float* fp = (float*)row;
#pragma unroll
    for (int c = 0; c < 24; ++c) fp[k * 24 + c] = M[c];  // floats [0,96)
  }
  __syncthreads();

  // ---- Reduce partials: thread (q = ql, comps sp*3..sp*3+2) ----
  {
    const float* fp = (const float*)row;
#pragma unroll
    for (int j0 = 0; j0 < 3; ++j0) {
      int j = sp * 3 + j0;
      float s = fp[0 * 24 + j] + fp[1 * 24 + j] + fp[2 * 24 + j] +
                fp[3 * 24 + j];
      sM[ql * 25 + j] = s;
    }
  }
  __syncthreads();

  // ---- Epilogue phase 2 (all waves): out[q][w*3+m], lane w = ql ----
  float wreg[NBASIS];
#pragma unroll
  for (int v = 0; v < NBASIS; ++v) wreg[v] = Wmat[v * OUTM + ql];
  const float scale = 0.022097086912079608f;  // (1/sqrt(8)) / 16
#pragma unroll
  for (int i = 0; i < 8; ++i) {
    int q = sp * 8 + i;  // wave-uniform -> sM broadcasts
    const float* mq = sM + q * 25;
    float a0 = 0.f, a1 = 0.f, a2 = 0.f;
#pragma unroll
    for (int v = 0; v < NBASIS; ++v) {
      a0 = fmaf(wreg[v], mq[v * 3 + 0], a0);
      a1 = fmaf(wreg[v], mq[v * 3 + 1], a1);
      a2 = fmaf(wreg[v], mq[v * 3 + 2], a2);
    }
    size_t o = (size_t)(base + qg * QPB + q) * (OUTM * 3) + ql * 3;
    out[o + 0] = a0 * scale;
    out[o + 1] = a1 * scale;
    out[o + 2] = a2 * scale;
  }
}

// coords [B*N][3] -> x/y/z planes + float4 array.
__global__ void prep_kernel(const float* __restrict__ coords,
                            float* __restrict__ Xp, float* __restrict__ Yp,
                            float* __restrict__ Zp, float4* __restrict__ cpad) {
  int i = blockIdx.x * 256 + threadIdx.x;
  if (i < NQTOT) {
    float x = coords[3 * i + 0];
    float y = coords[3 * i + 1];
    float z = coords[3 * i + 2];
    Xp[i] = x; Yp[i] = y; Zp[i] = z;
    cpad[i] = make_float4(x, y, z, 0.f);
  }
}

extern "C" void kernel_launch(void* const* d_in, const int* in_sizes, int n_in,
                              void* d_out, int out_size, void* d_ws, size_t ws_size,
                              hipStream_t stream) {
  const float* coords = (const float*)d_in[0];
  const float* Wmat = (const float*)d_in[1];
  float* out = (float*)d_out;

  char* w = (char*)d_ws;
  float* Xp = (float*)(w);               // 128 KB
  float* Yp = (float*)(w + 131072);
  float* Zp = (float*)(w + 262144);
  float4* cpad = (float4*)(w + 393216);  // 512 KB

  prep_kernel<<<dim3((NQTOT + 255) / 256), dim3(256), 0, stream>>>(coords, Xp, Yp, Zp, cpad);
  se3_kernel<<<dim3(NBATCH, NPTS / QPB), dim3(TKNN), 0, stream>>>(Xp, Yp, Zp, cpad, Wmat, out);
}

// Round 11
// 161.805 us; speedup vs baseline: 1.2950x; 1.0186x over previous
//
#include <hip/hip_runtime.h>

typedef unsigned int u32;
typedef unsigned long long u64;
typedef float v2f __attribute__((ext_vector_type(2)));

#define NBATCH 8
#define NPTS   4096
#define NQTOT  (NBATCH * NPTS)   /* 32768 */
#define KNN    16
#define NBASIS 8
#define OUTM   64
#define NSPLIT 8
#define WIN    (NPTS / NSPLIT)   /* 512 candidates per window */
#define QPB    64
#define TKNN   (QPB * NSPLIT)    /* 512 threads = 8 waves */
#define GRP    8
#define ECAP   64                /* synchronous digest: thr never stale ->
                                  * lambda ~16/phase, cap 64 proven (R3/R5/R7/R10) */
/* Admission margin: |(2(H-t)+qn) - d2_exact| <= ~2e-5 at these magnitudes
 * (coords ~N(0,1)); eps = 2e-4 gives 10x headroom. Admission is a SUPERSET
 * of the exact test; the digest recomputes exact d2 and discards extras ->
 * selection stays bit-identical. Mechanism proven in R10. */
#define THR_EPS 2e-4f
/* per-query LDS row (u64): [0,32) = 2 seed-funnel segments / 64-u32 entry
 * buffer / epilogue scratch; [32,48) = t16 (also 3rd funnel seg during seed);
 * [48] pad. 32 KB/block. */
#define ROWSTR 49
#define TOFF   32

// sentinel: d2 = +inf, idx = all-ones (sorts last)
#define SENT 0x7f800000ffffffffull

// Half-squared-norm plane H[i] = |c_i|^2 / 2. Static device global (128 KB):
// no workspace growth (ws stays at the R0-R7-proven 0.92 MB; statics proven
// safe by R9's g_part). Written by prep_kernel, read by the scan.
__device__ float g_H[NQTOT];

__device__ __forceinline__ void ce(u64& x, u64& y) {
  u64 a = x, b = y;
  bool sw = b < a;
  x = sw ? b : a;
  y = sw ? a : b;
}

// Batcher odd-even mergesort network (fully unrolled).
template <int N>
__device__ __forceinline__ void oems_sort(u64* a) {
#pragma unroll
  for (int p = 1; p < N; p <<= 1) {
#pragma unroll
    for (int k = p; k >= 1; k >>= 1) {
#pragma unroll
      for (int j = k & (p - 1); j + k < N; j += 2 * k) {
#pragma unroll
        for (int i = 0; i < k; ++i) {
          int lo = i + j, hi = i + j + k;
          if (hi < N && (lo / (2 * p)) == (hi / (2 * p)))
            ce(a[lo], a[hi]);
        }
      }
    }
  }
}

// t, a sorted asc -> t = smallest 16 of union, sorted asc.
__device__ __forceinline__ void merge16(u64 t[16], const u64 a[16]) {
  u64 m[16];
#pragma unroll
  for (int i = 0; i < 16; ++i) {
    u64 x = t[i], y = a[15 - i];
    m[i] = (x < y) ? x : y;
  }
#pragma unroll
  for (int k = 8; k >= 1; k >>= 1) {
#pragma unroll
    for (int i = 0; i < 16; ++i) {
      if ((i & k) == 0) ce(m[i], m[i | k]);
    }
  }
#pragma unroll
  for (int i = 0; i < 16; ++i) t[i] = m[i];
}

// Bit-exact d2 pair: ((dx^2+dy^2)+dz^2), no FMA contraction. v_pk ops round
// IEEE-identically to scalar (verified bit-exact vs reference rounds 0-10).
// Used where d2 becomes a SORT KEY (seed).
__device__ __forceinline__ v2f d2pair(v2f cx, v2f cy, v2f cz, v2f qx, v2f qy,
                                      v2f qz) {
#pragma clang fp contract(off)
  v2f dx = cx - qx;
  v2f dy = cy - qy;
  v2f dz = cz - qz;
  v2f d2 = (dx * dx + dy * dy) + dz * dz;
  return d2;
}

// Scalar bit-exact d2 (identical rounding to d2pair) — digest recompute.
// Proven bit-exact vs reference in rounds 1, 5, 6, 7, 10.
__device__ __forceinline__ float d2s(float cx, float cy, float cz, float qx,
                                     float qy, float qz) {
#pragma clang fp contract(off)
  float dx = cx - qx;
  float dy = cy - qy;
  float dz = cz - qz;
  return (dx * dx + dy * dy) + dz * dz;
}

// publish a sorted 16-list into funnel segment seg of this query's row
__device__ __forceinline__ void pub16(u64* row, int seg, const u64 s[16]) {
#pragma unroll
  for (int e = 0; e < 16; ++e) row[seg * 16 + e] = s[e];
}

// merge funnel segment seg into register list s
__device__ __forceinline__ void mrg16(const u64* row, int seg, u64 s[16]) {
  u64 a[16];
#pragma unroll
  for (int e = 0; e < 16; ++e) a[e] = row[seg * 16 + e];
  merge16(s, a);
}

// Fused kNN + tensor-product features — R10 structure (proven, 110.0us).
// R11 edit: scan admission in DOT-PRODUCT space. d2 <= thr+eps  <=>
// t = c.q >= H - rhs, rhs = (thr+eps-|q|^2)/2. Per pair: mul + 2 fma + sub
// = 4 packed ops vs 6 (d2fast) — and, unlike R1's failed attempt
// (fma(-X,qx,H): TWO sgpr operands/op -> v_mov padding, regressed), every
// op here reads at most ONE scalar-loaded operand:
//   t1 = X*qx (1s) ; t2 = fma(Y,qy,t1) (1s) ; t3 = fma(Z,qz,t2) (1s) ;
//   w = H - rhs (1s) ; cmp t3 >= w (0s).
// Digest discards false admits via exact keys -> selection bit-identical.
// Structure changes (R2/R6/R9) all regressed; only scan-issue cuts move the
// needle (R3/R5/R10). NO __launch_bounds__ min-waves (spills, measured).
__global__ __launch_bounds__(TKNN) void se3_kernel(
    const float* __restrict__ Xp, const float* __restrict__ Yp,
    const float* __restrict__ Zp, const float4* __restrict__ cpad,
    const float* __restrict__ Wmat, float* __restrict__ out) {
  __shared__ u64 sBuf[QPB * ROWSTR];  // 25.1 KB
  __shared__ u32 sCnt[QPB];
  __shared__ float sThr[QPB];
  __shared__ float sM[QPB * 25];      // reduced M[8][3], stride 25

  const int b = blockIdx.x;
  const int qg = blockIdx.y;
  const int tid = threadIdx.x;
  const int ql = tid & 63;
  const int sp = tid >> 6;  // window id, wave-uniform
  const int qi = qg * QPB + ql;
  const int base = b * NPTS;

  if (tid < QPB) sCnt[tid] = 0;

  // per-lane query coords (coalesced)
  const float qx = Xp[base + qi];
  const float qy = Yp[base + qi];
  const float qz = Zp[base + qi];
  const v2f qxx = {qx, qx}, qyy = {qy, qy}, qzz = {qz, qz};
  const float qn = qx * qx + qy * qy + qz * qz;

  // wave-uniform candidate window -> scalar loads feeding packed math
  const int wbase = __builtin_amdgcn_readfirstlane(sp * WIN);
  const v2f* xs2 = (const v2f*)(Xp + base + wbase);
  const v2f* ys2 = (const v2f*)(Yp + base + wbase);
  const v2f* zs2 = (const v2f*)(Zp + base + wbase);
  const v2f* hs2 = (const v2f*)(g_H + base + wbase);
  const int sj = qi - wbase;  // self position inside window (may be OOR)

  u64* row = sBuf + (size_t)ql * ROWSTR;

  // ---- Seed: every wave sorts its window's first 16; 3-seg tree merge ----
  // (exact d2 — these values become sort keys directly)
  {
    u64 s16[16];
    float cd[16];
#pragma unroll
    for (int p = 0; p < 8; ++p) {
      v2f d2 = d2pair(xs2[p], ys2[p], zs2[p], qxx, qyy, qzz);
      cd[2 * p + 0] = d2.x;
      cd[2 * p + 1] = d2.y;
    }
#pragma unroll
    for (int i = 0; i < 16; ++i) {
      u64 v = ((u64)__float_as_uint(cd[i]) << 32) | (u32)(wbase + i);
      s16[i] = (i == sj) ? SENT : v;
    }
    oems_sort<16>(s16);

    // P1: w5,w6,w7 -> segs 0,1,2 (seg2 = t16 region, free during seed)
    if (sp >= 5) pub16(row, sp - 5, s16);
    __syncthreads();
    if (sp >= 1 && sp <= 3) mrg16(row, sp - 1, s16);  // {1,5} {2,6} {3,7}
    __syncthreads();
    // P2: w4 -> seg0, w3 -> seg1
    if (sp == 4) pub16(row, 0, s16);
    if (sp == 3) pub16(row, 1, s16);
    __syncthreads();
    if (sp == 0) mrg16(row, 0, s16);  // {0,4}
    if (sp == 1) mrg16(row, 1, s16);  // {1,5,3,7}
    __syncthreads();
    // P3: w2 -> seg0, w1 -> seg1
    if (sp == 2) pub16(row, 0, s16);
    if (sp == 1) pub16(row, 1, s16);
    __syncthreads();
    if (sp == 0) {
      mrg16(row, 0, s16);  // {0,4,2,6}
      mrg16(row, 1, s16);  // all 8 windows
#pragma unroll
      for (int e = 0; e < 16; ++e) row[TOFF + e] = s16[e];
      sThr[ql] = __uint_as_float((u32)(s16[15] >> 32));
    }
    __syncthreads();
  }
  float thr = sThr[ql];
  // dot-space threshold: admit iff c.q >= H - rhs
  float rhs = 0.5f * (thr + THR_EPS - qn);
  v2f rhsv = {rhs, rhs};

  // self-exclusion mask precompute (avoids per-candidate j!=qi compare)
  const int selfgrp = (sj >= 0 && sj < WIN) ? (sj >> 3) : -1;
  const u32 selfbit = 1u << (sj & 7);

  // entry buffer: u32 slots [0,64) of the row = u64 slots [0,32)
  u32* ebuf = (u32*)row;

  // ---- Main scan: doubling phases; digest wave rotates (1..5) ----
#pragma unroll
  for (int ph = 0; ph < 5; ++ph) {
    const int cstart = 16 << ph;  // [16,32),[32,64),...,[256,512)
    const int cend = 32 << ph;
#pragma unroll 2
    for (int g = cstart; g < cend; g += GRP) {
      v2f tdot[4], wcut[4];
#pragma unroll
      for (int p = 0; p < 4; ++p) {
        const int ix = (g >> 1) + p;
        v2f t1 = xs2[ix] * qxx;                              // 1 sgpr
        v2f t2 = __builtin_elementwise_fma(ys2[ix], qyy, t1);  // 1 sgpr
        tdot[p] = __builtin_elementwise_fma(zs2[ix], qzz, t2); // 1 sgpr
        wcut[p] = hs2[ix] - rhsv;                            // 1 sgpr
      }
      u32 want = 0;
#pragma unroll
      for (int i = 0; i < GRP; ++i)
        want |= (tdot[i >> 1][i & 1] >= wcut[i >> 1][i & 1]) ? (1u << i) : 0u;
      if ((g >> 3) == selfgrp) want &= ~selfbit;
      if (want) {  // ONE u32 entry per group with any hit
        u32 slot = atomicAdd(&sCnt[ql], 1u);
        if (slot < ECAP) ebuf[slot] = (want << 12) | (u32)(wbase + g);
      }
    }
    __syncthreads();
    if (sp == ph + 1) {  // rotating digest wave (1..5), between barriers
      int n = (int)sCnt[ql];
      n = n < ECAP ? n : ECAP;
      if (__any(n > 0)) {
        u64 t16[16];
#pragma unroll
        for (int e = 0; e < 16; ++e) t16[e] = row[TOFF + e];
        int cursor = 0;
        u32 curWant = 0, curBase = 0;
        while (__any(cursor < n || curWant != 0)) {
          // pass 1: decode up to 16 candidate indices (VALU only)
          u32 kidx[16];
          u32 vmask = 0;
#pragma unroll
          for (int e = 0; e < 16; ++e) {
            if (curWant == 0 && cursor < n) {
              u32 ent = ebuf[cursor++];
              curWant = ent >> 12;
              curBase = ent & 0xFFFu;
            }
            if (curWant) {
              int bit = __ffs(curWant) - 1;
              curWant &= curWant - 1;
              kidx[e] = curBase + (u32)bit;
              vmask |= (1u << e);
            } else {
              kidx[e] = 0;
            }
          }
          // pass 2: batched gathers + bit-exact d2 recompute
          u64 a[16];
#pragma unroll
          for (int e = 0; e < 16; ++e) {
            float4 c = cpad[base + (int)kidx[e]];
            float d2 = d2s(c.x, c.y, c.z, qx, qy, qz);
            u64 key = ((u64)__float_as_uint(d2) << 32) | kidx[e];
            a[e] = (vmask & (1u << e)) ? key : SENT;
          }
          oems_sort<16>(a);
          merge16(t16, a);
        }
#pragma unroll
        for (int e = 0; e < 16; ++e) row[TOFF + e] = t16[e];
        sThr[ql] = __uint_as_float((u32)(t16[15] >> 32));
      }
      sCnt[ql] = 0;
    }
    __syncthreads();
    thr = sThr[ql];
    rhs = 0.5f * (thr + THR_EPS - qn);
    rhsv.x = rhs;
    rhsv.y = rhs;
  }

  // ---- Epilogue phase 1 (waves 0-3): partial M over 4 neighbors each ----
  // pv is read by ALL participating threads first; the barrier then orders
  // those reads before scratch writes clobber the t16 region (row floats
  // [0,96) = the whole row incl. t16 floats [64,96), all dead afterward).
  u64 pv[4];
  if (sp < 4) {
#pragma unroll
    for (int e = 0; e < 4; ++e) pv[e] = row[TOFF + sp * 4 + e];
  }
  __syncthreads();
  if (sp < 4) {
    const int k = sp;
    float4 nc[4];
    float dd[4];
#pragma unroll
    for (int e = 0; e < 4; ++e) {
      nc[e] = cpad[base + (int)(u32)pv[e]];  // independent gathers
      dd[e] = __uint_as_float((u32)(pv[e] >> 32));
    }
    float M[24];
#pragma unroll
    for (int j = 0; j < 24; ++j) M[j] = 0.f;
#pragma unroll
    for (int e = 0; e < 4; ++e) {
      float rx = nc[e].x - qx;  // sender - receiver
      float ry = nc[e].y - qy;
      float rz = nc[e].z - qz;
      float dist = sqrtf(dd[e]);
      float inv = 1.0f / (dist + 1e-8f);
      rx *= inv; ry *= inv; rz *= inv;
      float cut = fminf(dist * 0.1f, 1.0f);
      float g[NBASIS], s = 0.f;
#pragma unroll
      for (int v = 0; v < NBASIS; ++v) {
        float t = cut - (float)v * (1.0f / 7.0f);
        g[v] = __expf(-32.0f * t * t);  // sigma = 1/8 -> 1/(2s^2) = 32
        s += g[v];
      }
      float rs = 1.0f / s;
#pragma unroll
      for (int v = 0; v < NBASIS; ++v) {
        float rb = g[v] * rs;
        M[v * 3 + 0] = fmaf(rb, rx, M[v * 3 + 0]);
        M[v * 3 + 1] = fmaf(rb, ry, M[v * 3 + 1]);
        M[v * 3 + 2] = fmaf(rb, rz, M[v * 3 + 2]);
      }
    }
    float* fp = (float*)row;
#pragma unroll
    for (int c = 0; c < 24; ++c) fp[k * 24 + c] = M[c];  // floats [0,96)
  }
  __syncthreads();

  // ---- Reduce partials: thread (q = ql, comps sp*3..sp*3+2) ----
  {
    const float* fp = (const float*)row;
#pragma unroll
    for (int j0 = 0; j0 < 3; ++j0) {
      int j = sp * 3 + j0;
      float s = fp[0 * 24 + j] + fp[1 * 24 + j] + fp[2 * 24 + j] +
                fp[3 * 24 + j];
      sM[ql * 25 + j] = s;
    }
  }
  __syncthreads();

  // ---- Epilogue phase 2 (all waves): out[q][w*3+m], lane w = ql ----
  float wreg[NBASIS];
#pragma unroll
  for (int v = 0; v < NBASIS; ++v) wreg[v] = Wmat[v * OUTM + ql];
  const float scale = 0.022097086912079608f;  // (1/sqrt(8)) / 16
#pragma unroll
  for (int i = 0; i < 8; ++i) {
    int q = sp * 8 + i;  // wave-uniform -> sM broadcasts
    const float* mq = sM + q * 25;
    float a0 = 0.f, a1 = 0.f, a2 = 0.f;
#pragma unroll
    for (int v = 0; v < NBASIS; ++v) {
      a0 = fmaf(wreg[v], mq[v * 3 + 0], a0);
      a1 = fmaf(wreg[v], mq[v * 3 + 1], a1);
      a2 = fmaf(wreg[v], mq[v * 3 + 2], a2);
    }
    size_t o = (size_t)(base + qg * QPB + q) * (OUTM * 3) + ql * 3;
    out[o + 0] = a0 * scale;
    out[o + 1] = a1 * scale;
    out[o + 2] = a2 * scale;
  }
}

// coords [B*N][3] -> x/y/z planes + float4 array + half-norm plane.
__global__ void prep_kernel(const float* __restrict__ coords,
                            float* __restrict__ Xp, float* __restrict__ Yp,
                            float* __restrict__ Zp, float4* __restrict__ cpad) {
  int i = blockIdx.x * 256 + threadIdx.x;
  if (i < NQTOT) {
    float x = coords[3 * i + 0];
    float y = coords[3 * i + 1];
    float z = coords[3 * i + 2];
    Xp[i] = x; Yp[i] = y; Zp[i] = z;
    cpad[i] = make_float4(x, y, z, 0.f);
    g_H[i] = 0.5f * (x * x + y * y + z * z);
  }
}

extern "C" void kernel_launch(void* const* d_in, const int* in_sizes, int n_in,
                              void* d_out, int out_size, void* d_ws, size_t ws_size,
                              hipStream_t stream) {
  const float* coords = (const float*)d_in[0];
  const float* Wmat = (const float*)d_in[1];
  float* out = (float*)d_out;

  char* w = (char*)d_ws;
  float* Xp = (float*)(w);               // 128 KB
  float* Yp = (float*)(w + 131072);
  float* Zp = (float*)(w + 262144);
  float4* cpad = (float4*)(w + 393216);  // 512 KB; ws use = 0.92 MB (proven)

  prep_kernel<<<dim3((NQTOT + 255) / 256), dim3(256), 0, stream>>>(coords, Xp, Yp, Zp, cpad);
  se3_kernel<<<dim3(NBATCH, NPTS / QPB), dim3(TKNN), 0, stream>>>(Xp, Yp, Zp, cpad, Wmat, out);
}

// Round 13
// 154.722 us; speedup vs baseline: 1.3542x; 1.0458x over previous
//
#include <hip/hip_runtime.h>

typedef unsigned int u32;
typedef unsigned long long u64;
typedef float v2f __attribute__((ext_vector_type(2)));

#define NBATCH 8
#define NPTS   4096
#define NQTOT  (NBATCH * NPTS)   /* 32768 */
#define KNN    16
#define NBASIS 8
#define OUTM   64
#define NSPLIT 8
#define WIN    (NPTS / NSPLIT)   /* 512 candidates per window */
#define QPB    64
#define TKNN   (QPB * NSPLIT)    /* 512 threads = 8 waves */
#define GRP    16
/* CAPACITY MODEL (R12 failure lesson): thr is STATIC within a phase, so
 * per-phase admissions are Binomial(new_candidates, ~16/seen) — E=16/query
 * per DOUBLING phase (T_s tightens 2x as candidates double). ECAP=64 =
 * mean+13sigma. R12's quadrupling phases had E=48 -> 0.7%/query overflow ->
 * absmax 0.105. Doubling phases + cap 64 proven across R3/R5/R7/R10/R11. */
#define ECAP   64
/* Admission margin: |approx_d2 - exact_d2| <= ~2e-5 at these magnitudes for
 * any of the fma-contracted forms used here; eps = 2e-4 gives 10x headroom.
 * Admission is a SUPERSET of the exact test; the digest recomputes exact d2
 * and discards extras -> selection bit-identical. Proven R10/R11. */
#define THR_EPS 2e-4f
/* per-query LDS row (u64): [0,32) = 2 seed-funnel segments / 64-u32 entry
 * buffer / epilogue scratch; [32,48) = t16 (also 3rd funnel seg during seed);
 * [48] pad. 32 KB/block. */
#define ROWSTR 49
#define TOFF   32

// sentinel: d2 = +inf, idx = all-ones (sorts last)
#define SENT 0x7f800000ffffffffull

// Half-squared-norm plane H[i] = |c_i|^2 / 2. Static device global (128 KB):
// no workspace growth; statics proven safe (R9/R11).
__device__ float g_H[NQTOT];

__device__ __forceinline__ void ce(u64& x, u64& y) {
  u64 a = x, b = y;
  bool sw = b < a;
  x = sw ? b : a;
  y = sw ? a : b;
}

// Batcher odd-even mergesort network (fully unrolled).
template <int N>
__device__ __forceinline__ void oems_sort(u64* a) {
#pragma unroll
  for (int p = 1; p < N; p <<= 1) {
#pragma unroll
    for (int k = p; k >= 1; k >>= 1) {
#pragma unroll
      for (int j = k & (p - 1); j + k < N; j += 2 * k) {
#pragma unroll
        for (int i = 0; i < k; ++i) {
          int lo = i + j, hi = i + j + k;
          if (hi < N && (lo / (2 * p)) == (hi / (2 * p)))
            ce(a[lo], a[hi]);
        }
      }
    }
  }
}

// t, a sorted asc -> t = smallest 16 of union, sorted asc.
__device__ __forceinline__ void merge16(u64 t[16], const u64 a[16]) {
  u64 m[16];
#pragma unroll
  for (int i = 0; i < 16; ++i) {
    u64 x = t[i], y = a[15 - i];
    m[i] = (x < y) ? x : y;
  }
#pragma unroll
  for (int k = 8; k >= 1; k >>= 1) {
#pragma unroll
    for (int i = 0; i < 16; ++i) {
      if ((i & k) == 0) ce(m[i], m[i | k]);
    }
  }
#pragma unroll
  for (int i = 0; i < 16; ++i) t[i] = m[i];
}

// Bit-exact d2 pair: ((dx^2+dy^2)+dz^2), no FMA contraction. v_pk ops round
// IEEE-identically to scalar (verified bit-exact vs reference rounds 0-11).
// Used where d2 becomes a SORT KEY (seed).
__device__ __forceinline__ v2f d2pair(v2f cx, v2f cy, v2f cz, v2f qx, v2f qy,
                                      v2f qz) {
#pragma clang fp contract(off)
  v2f dx = cx - qx;
  v2f dy = cy - qy;
  v2f dz = cz - qz;
  v2f d2 = (dx * dx + dy * dy) + dz * dz;
  return d2;
}

// Scalar bit-exact d2 (identical rounding to d2pair) — digest recompute.
// Proven bit-exact vs reference in rounds 1, 5, 6, 7, 10, 11.
__device__ __forceinline__ float d2s(float cx, float cy, float cz, float qx,
                                     float qy, float qz) {
#pragma clang fp contract(off)
  float dx = cx - qx;
  float dy = cy - qy;
  float dz = cz - qz;
  return (dx * dx + dy * dy) + dz * dz;
}

// publish a sorted 16-list into funnel segment seg of this query's row
__device__ __forceinline__ void pub16(u64* row, int seg, const u64 s[16]) {
#pragma unroll
  for (int e = 0; e < 16; ++e) row[seg * 16 + e] = s[e];
}

// merge funnel segment seg into register list s
__device__ __forceinline__ void mrg16(const u64* row, int seg, u64 s[16]) {
  u64 a[16];
#pragma unroll
  for (int e = 0; e < 16; ++e) a[e] = row[seg * 16 + e];
  merge16(s, a);
}

// Fused kNN + tensor-product features — R11 structure (proven, 107.2us:
// 512-thread blocks, 8 windows, 5 DOUBLING phases, rotating single-wave
// digest — lane-efficient: 64 lanes = 64 queries; R12's 8-lane distributed
// digest issued 8x total instructions and its quad-phases overflowed ECAP).
// R13 edits (scan ALU only, deterministic):
//  (e) rhs folded into the fma chain: t = fma(z,qz,fma(y,qy,fma(x,qx,rhs)));
//      admit iff t >= H. Kills the per-pair wcut sub. Every op <= 1 scalar
//      operand (R1's 2-sgpr lesson).
//  (f) GRP 8->16: halves per-group fixed overhead (selfgrp check, want
//      branch, atomic path). Entry (want16<<12)|base fits u32 (base<4096).
// Digest discards false admits via exact keys -> selection bit-identical.
// NO __launch_bounds__ min-waves (spills, measured).
__global__ __launch_bounds__(TKNN) void se3_kernel(
    const float* __restrict__ Xp, const float* __restrict__ Yp,
    const float* __restrict__ Zp, const float4* __restrict__ cpad,
    const float* __restrict__ Wmat, float* __restrict__ out) {
  __shared__ u64 sBuf[QPB * ROWSTR];  // 25.1 KB
  __shared__ u32 sCnt[QPB];
  __shared__ float sThr[QPB];
  __shared__ float sM[QPB * 25];      // reduced M[8][3], stride 25

  const int b = blockIdx.x;
  const int qg = blockIdx.y;
  const int tid = threadIdx.x;
  const int ql = tid & 63;
  const int sp = tid >> 6;  // window id, wave-uniform
  const int qi = qg * QPB + ql;
  const int base = b * NPTS;

  if (tid < QPB) sCnt[tid] = 0;

  // per-lane query coords (coalesced)
  const float qx = Xp[base + qi];
  const float qy = Yp[base + qi];
  const float qz = Zp[base + qi];
  const v2f qxx = {qx, qx}, qyy = {qy, qy}, qzz = {qz, qz};
  const float qn = qx * qx + qy * qy + qz * qz;

  // wave-uniform candidate window -> scalar loads feeding packed math
  const int wbase = __builtin_amdgcn_readfirstlane(sp * WIN);
  const v2f* xs2 = (const v2f*)(Xp + base + wbase);
  const v2f* ys2 = (const v2f*)(Yp + base + wbase);
  const v2f* zs2 = (const v2f*)(Zp + base + wbase);
  const v2f* hs2 = (const v2f*)(g_H + base + wbase);
  const int sj = qi - wbase;  // self position inside window (may be OOR)

  u64* row = sBuf + (size_t)ql * ROWSTR;

  // ---- Seed: every wave sorts its window's first 16; 3-seg tree merge ----
  // (exact d2 — these values become sort keys directly)
  {
    u64 s16[16];
    float cd[16];
#pragma unroll
    for (int p = 0; p < 8; ++p) {
      v2f d2 = d2pair(xs2[p], ys2[p], zs2[p], qxx, qyy, qzz);
      cd[2 * p + 0] = d2.x;
      cd[2 * p + 1] = d2.y;
    }
#pragma unroll
    for (int i = 0; i < 16; ++i) {
      u64 v = ((u64)__float_as_uint(cd[i]) << 32) | (u32)(wbase + i);
      s16[i] = (i == sj) ? SENT : v;
    }
    oems_sort<16>(s16);

    // P1: w5,w6,w7 -> segs 0,1,2 (seg2 = t16 region, free during seed)
    if (sp >= 5) pub16(row, sp - 5, s16);
    __syncthreads();
    if (sp >= 1 && sp <= 3) mrg16(row, sp - 1, s16);  // {1,5} {2,6} {3,7}
    __syncthreads();
    // P2: w4 -> seg0, w3 -> seg1
    if (sp == 4) pub16(row, 0, s16);
    if (sp == 3) pub16(row, 1, s16);
    __syncthreads();
    if (sp == 0) mrg16(row, 0, s16);  // {0,4}
    if (sp == 1) mrg16(row, 1, s16);  // {1,5,3,7}
    __syncthreads();
    // P3: w2 -> seg0, w1 -> seg1
    if (sp == 2) pub16(row, 0, s16);
    if (sp == 1) pub16(row, 1, s16);
    __syncthreads();
    if (sp == 0) {
      mrg16(row, 0, s16);  // {0,4,2,6}
      mrg16(row, 1, s16);  // all 8 windows
#pragma unroll
      for (int e = 0; e < 16; ++e) row[TOFF + e] = s16[e];
      sThr[ql] = __uint_as_float((u32)(s16[15] >> 32));
    }
    __syncthreads();
  }
  float thr = sThr[ql];
  // dot-space threshold: admit iff c.q + rhs >= H
  float rhs = 0.5f * (thr + THR_EPS - qn);
  v2f rhsv = {rhs, rhs};

  // self-exclusion mask precompute (GRP=16 groups)
  const int selfgrp = (sj >= 0 && sj < WIN) ? (sj >> 4) : -1;
  const u32 selfbit = 1u << (sj & 15);

  // entry buffer: u32 slots [0,64) of the row = u64 slots [0,32)
  u32* ebuf = (u32*)row;

  // ---- Main scan: 5 doubling phases; digest wave rotates (1..5) ----
#pragma unroll
  for (int ph = 0; ph < 5; ++ph) {
    const int cstart = 16 << ph;  // [16,32),[32,64),...,[256,512)
    const int cend = 32 << ph;
#pragma unroll 2
    for (int g = cstart; g < cend; g += GRP) {
      v2f tdot[8];
#pragma unroll
      for (int p = 0; p < 8; ++p) {
        const int ix = (g >> 1) + p;
        v2f t1 = __builtin_elementwise_fma(xs2[ix], qxx, rhsv);  // 1 sgpr
        v2f t2 = __builtin_elementwise_fma(ys2[ix], qyy, t1);    // 1 sgpr
        tdot[p] = __builtin_elementwise_fma(zs2[ix], qzz, t2);   // 1 sgpr
      }
      u32 want = 0;
#pragma unroll
      for (int i = 0; i < GRP; ++i)
        want |= (tdot[i >> 1][i & 1] >= hs2[(g >> 1) + (i >> 1)][i & 1])
                    ? (1u << i)
                    : 0u;  // cmp vs scalar-loaded H: 1 sgpr
      if ((g >> 4) == selfgrp) want &= ~selfbit;
      if (want) {  // ONE u32 entry per group-of-16 with any hit
        u32 slot = atomicAdd(&sCnt[ql], 1u);
        if (slot < ECAP) ebuf[slot] = (want << 12) | (u32)(wbase + g);
      }
    }
    __syncthreads();
    if (sp == ph + 1) {  // rotating digest wave (1..5), between barriers
      int n = (int)sCnt[ql];
      n = n < ECAP ? n : ECAP;
      if (__any(n > 0)) {
        u64 t16[16];
#pragma unroll
        for (int e = 0; e < 16; ++e) t16[e] = row[TOFF + e];
        int cursor = 0;
        u32 curWant = 0, curBase = 0;
        while (__any(cursor < n || curWant != 0)) {
          // pass 1: decode up to 16 candidate indices (VALU only)
          u32 kidx[16];
          u32 vmask = 0;
#pragma unroll
          for (int e = 0; e < 16; ++e) {
            if (curWant == 0 && cursor < n) {
              u32 ent = ebuf[cursor++];
              curWant = ent >> 12;
              curBase = ent & 0xFFFu;
            }
            if (curWant) {
              int bit = __ffs(curWant) - 1;
              curWant &= curWant - 1;
              kidx[e] = curBase + (u32)bit;
              vmask |= (1u << e);
            } else {
              kidx[e] = 0;
            }
          }
          // pass 2: batched gathers + bit-exact d2 recompute
          u64 a[16];
#pragma unroll
          for (int e = 0; e < 16; ++e) {
            float4 c = cpad[base + (int)kidx[e]];
            float d2 = d2s(c.x, c.y, c.z, qx, qy, qz);
            u64 key = ((u64)__float_as_uint(d2) << 32) | kidx[e];
            a[e] = (vmask & (1u << e)) ? key : SENT;
          }
          oems_sort<16>(a);
          merge16(t16, a);
        }
#pragma unroll
        for (int e = 0; e < 16; ++e) row[TOFF + e] = t16[e];
        sThr[ql] = __uint_as_float((u32)(t16[15] >> 32));
      }
      sCnt[ql] = 0;
    }
    __syncthreads();
    thr = sThr[ql];
    rhs = 0.5f * (thr + THR_EPS - qn);
    rhsv.x = rhs;
    rhsv.y = rhs;
  }

  // ---- Epilogue phase 1 (waves 0-3): partial M over 4 neighbors each ----
  // pv is read by ALL participating threads first; the barrier then orders
  // those reads before scratch writes clobber the t16 region (row floats
  // [0,96) = the whole row incl. t16 floats [64,96), all dead afterward).
  u64 pv[4];
  if (sp < 4) {
#pragma unroll
    for (int e = 0; e < 4; ++e) pv[e] = row[TOFF + sp * 4 + e];
  }
  __syncthreads();
  if (sp < 4) {
    const int k = sp;
    float4 nc[4];
    float dd[4];
#pragma unroll
    for (int e = 0; e < 4; ++e) {
      nc[e] = cpad[base + (int)(u32)pv[e]];  // independent gathers
      dd[e] = __uint_as_float((u32)(pv[e] >> 32));
    }
    float M[24];
#pragma unroll
    for (int j = 0; j < 24; ++j) M[j] = 0.f;
#pragma unroll
    for (int e = 0; e < 4; ++e) {
      float rx = nc[e].x - qx;  // sender - receiver
      float ry = nc[e].y - qy;
      float rz = nc[e].z - qz;
      float dist = sqrtf(dd[e]);
      float inv = 1.0f / (dist + 1e-8f);
      rx *= inv; ry *= inv; rz *= inv;
      float cut = fminf(dist * 0.1f, 1.0f);
      float g[NBASIS], s = 0.f;
#pragma unroll
      for (int v = 0; v < NBASIS; ++v) {
        float t = cut - (float)v * (1.0f / 7.0f);
        g[v] = __expf(-32.0f * t * t);  // sigma = 1/8 -> 1/(2s^2) = 32
        s += g[v];
      }
      float rs = 1.0f / s;
#pragma unroll
      for (int v = 0; v < NBASIS; ++v) {
        float rb = g[v] * rs;
        M[v * 3 + 0] = fmaf(rb, rx, M[v * 3 + 0]);
        M[v * 3 + 1] = fmaf(rb, ry, M[v * 3 + 1]);
        M[v * 3 + 2] = fmaf(rb, rz, M[v * 3 + 2]);
      }
    }
    float* fp = (float*)row;
#pragma unroll
    for (int c = 0; c < 24; ++c) fp[k * 24 + c] = M[c];  // floats [0,96)
  }
  __syncthreads();

  // ---- Reduce partials: thread (q = ql, comps sp*3..sp*3+2) ----
  {
    const float* fp = (const float*)row;
#pragma unroll
    for (int j0 = 0; j0 < 3; ++j0) {
      int j = sp * 3 + j0;
      float s = fp[0 * 24 + j] + fp[1 * 24 + j] + fp[2 * 24 + j] +
                fp[3 * 24 + j];
      sM[ql * 25 + j] = s;
    }
  }
  __syncthreads();

  // ---- Epilogue phase 2 (all waves): out[q][w*3+m], lane w = ql ----
  float wreg[NBASIS];
#pragma unroll
  for (int v = 0; v < NBASIS; ++v) wreg[v] = Wmat[v * OUTM + ql];
  const float scale = 0.022097086912079608f;  // (1/sqrt(8)) / 16
#pragma unroll
  for (int i = 0; i < 8; ++i) {
    int q = sp * 8 + i;  // wave-uniform -> sM broadcasts
    const float* mq = sM + q * 25;
    float a0 = 0.f, a1 = 0.f, a2 = 0.f;
#pragma unroll
    for (int v = 0; v < NBASIS; ++v) {
      a0 = fmaf(wreg[v], mq[v * 3 + 0], a0);
      a1 = fmaf(wreg[v], mq[v * 3 + 1], a1);
      a2 = fmaf(wreg[v], mq[v * 3 + 2], a2);
    }
    size_t o = (size_t)(base + qg * QPB + q) * (OUTM * 3) + ql * 3;
    out[o + 0] = a0 * scale;
    out[o + 1] = a1 * scale;
    out[o + 2] = a2 * scale;
  }
}

// coords [B*N][3] -> x/y/z planes + float4 array + half-norm plane.
__global__ void prep_kernel(const float* __restrict__ coords,
                            float* __restrict__ Xp, float* __restrict__ Yp,
                            float* __restrict__ Zp, float4* __restrict__ cpad) {
  int i = blockIdx.x * 256 + threadIdx.x;
  if (i < NQTOT) {
    float x = coords[3 * i + 0];
    float y = coords[3 * i + 1];
    float z = coords[3 * i + 2];
    Xp[i] = x; Yp[i] = y; Zp[i] = z;
    cpad[i] = make_float4(x, y, z, 0.f);
    g_H[i] = 0.5f * (x * x + y * y + z * z);
  }
}

extern "C" void kernel_launch(void* const* d_in, const int* in_sizes, int n_in,
                              void* d_out, int out_size, void* d_ws, size_t ws_size,
                              hipStream_t stream) {
  const float* coords = (const float*)d_in[0];
  const float* Wmat = (const float*)d_in[1];
  float* out = (float*)d_out;

  char* w = (char*)d_ws;
  float* Xp = (float*)(w);               // 128 KB
  float* Yp = (float*)(w + 131072);
  float* Zp = (float*)(w + 262144);
  float4* cpad = (float4*)(w + 393216);  // 512 KB; ws use = 0.92 MB (proven)

  prep_kernel<<<dim3((NQTOT + 255) / 256), dim3(256), 0, stream>>>(coords, Xp, Yp, Zp, cpad);
  se3_kernel<<<dim3(NBATCH, NPTS / QPB), dim3(TKNN), 0, stream>>>(Xp, Yp, Zp, cpad, Wmat, out);
}